// Round 8
// baseline (190.381 us; speedup 1.0000x reference)
//
#include <hip/hip_runtime.h>
#include <hip/hip_bf16.h>
#include <stdint.h>

// ---------------------------------------------------------------------------
// Loss_29592324669863, round 8.
//  Persistent fused Gram kernel, BK=128: 256 blocks (1/CU), 8 waves, per-wave
//  32x64, 2 steps/tile (32 MFMA + 24 ds_read per wave per step -> half the
//  barrier/waitcnt overhead of r5-r7). Cross-tile counted-vmcnt pipeline;
//  labels gload_lds-staged into parity-dbuf labS. Contiguous per-XCD tile
//  ranges (3632 = 8*454) restore L2 locality lost in r7.
// ---------------------------------------------------------------------------

typedef __attribute__((ext_vector_type(8))) short bf16x8;   // 8 bf16 = 4 VGPR
typedef __attribute__((ext_vector_type(4))) float f32x4;

__device__ inline void gload_lds16(const void* g, void* l) {
  __builtin_amdgcn_global_load_lds(
      (__attribute__((address_space(1))) void*)g,
      (__attribute__((address_space(3))) void*)l, 16, 0, 0);
}

__device__ inline void barrier_raw() {
  asm volatile("" ::: "memory");
  __builtin_amdgcn_s_barrier();
  asm volatile("" ::: "memory");
}

__device__ inline void lgkm_barrier() {   // order LDS ops, keep vmcnt queue
  asm volatile("s_waitcnt lgkmcnt(0)" ::: "memory");
  __builtin_amdgcn_s_barrier();
  asm volatile("" ::: "memory");
}

__device__ inline unsigned short f2bf(float x) {  // RNE f32->bf16
  unsigned int u = __builtin_bit_cast(unsigned int, x);
  u = (u + 0x7fffu + ((u >> 16) & 1u)) >> 16;
  return (unsigned short)u;
}

// ---------------------------------------------------------------------------
__global__ __launch_bounds__(256) void norm_kernel(
    const float* __restrict__ LE, const float* __restrict__ FZ,
    const float* __restrict__ SE, const float* __restrict__ LM,
    unsigned short* __restrict__ An, unsigned short* __restrict__ Fn,
    unsigned short* __restrict__ Sn, unsigned short* __restrict__ Ln,
    float* __restrict__ hacc, float* __restrict__ out) {
  const int tid = threadIdx.x;
  if (blockIdx.x == 0) {        // zero accumulators for this call
    if (tid == 0) out[0] = 0.f;
    if (tid == 1) out[1] = 0.f;
    if (tid == 2) hacc[0] = 0.f;
  }

  const int wid = tid >> 6, lane = tid & 63;
  const int row = blockIdx.x * 4 + wid;

  const float* src;
  unsigned short* dst;
  int r;
  if (row < 4096)       { src = LE; dst = An; r = row; }
  else if (row < 12288) { src = FZ; dst = Fn; r = row - 4096; }
  else if (row < 16384) { src = SE; dst = Sn; r = row - 12288; }
  else                  { src = LM; dst = Ln; r = row - 16384; }

  const float4 v = *(const float4*)(src + (size_t)r * 256 + lane * 4);
  float ss = v.x * v.x + v.y * v.y + v.z * v.z + v.w * v.w;
#pragma unroll
  for (int m = 1; m < 64; m <<= 1) ss += __shfl_xor(ss, m);
  const float scale = 1.0f / fmaxf(sqrtf(ss), 1e-8f);

  ushort4 o;
  o.x = f2bf(v.x * scale);
  o.y = f2bf(v.y * scale);
  o.z = f2bf(v.z * scale);
  o.w = f2bf(v.w * scale);
  *(ushort4*)(dst + (size_t)r * 256 + lane * 4) = o;
}

// ---------------------------------------------------------------------------
__device__ inline void tri_decode(int t, int nb, int& rb, int& cb) {
  int r = 0;
  while (t >= nb - r) { t -= nb - r; ++r; }
  rb = r;
  cb = r + t;
}

__device__ inline void decode_tile(
    int bid, const unsigned short* An, const unsigned short* Fn,
    const unsigned short* Sn, const unsigned short* Ln, int& mode, int& rb,
    int& cb, const unsigned short*& X, const unsigned short*& Y) {
  if (bid < 528) {            // class: tri over 32x32 panels
    mode = 0; tri_decode(bid, 32, rb, cb); X = An; Y = An;
  } else if (bid < 2608) {    // cross: tri over 64x64 panels
    mode = 1; tri_decode(bid - 528, 64, rb, cb); X = Fn; Y = Fn;
  } else {                    // hash: full 32x32
    mode = 2; const int t = bid - 2608; rb = t >> 5; cb = t & 31;
    X = Sn; Y = Ln;
  }
}

// ---------------------------------------------------------------------------
// Persistent fused Gram kernel: 8 waves (4x2), per-wave 32x64, BK=128 dbuf.
// LDS rows 256B = 16 granules; phys granule = logical ^ (row&15), applied on
// pre-swizzled GLOBAL src (LDS write linear) and on ds_read addrs.
// ---------------------------------------------------------------------------
__global__ __launch_bounds__(512, 2) void fused_sim(
    const unsigned short* __restrict__ An, const unsigned short* __restrict__ Fn,
    const unsigned short* __restrict__ Sn, const unsigned short* __restrict__ Ln,
    const int* __restrict__ labels,
    const float* __restrict__ tp, const float* __restrict__ xip,
    float2* __restrict__ Pc,   // [32 slots][4096 rows] (num,den)
    float2* __restrict__ Px,   // [64 slots][8192 rows]
    float* __restrict__ hacc) {
  __shared__ __align__(16) char Ab[2][32768];   // [buf][128 rows x 256B]
  __shared__ __align__(16) char Bb[2][32768];
  __shared__ __align__(16) int labS[2][256];    // [parity][row 128 | col 128]
  __shared__ float sN[256], sD[256], cN[512], cD[512];  // epilogue scratch

  const int tid = threadIdx.x;
  const int lane = tid & 63, wid = tid >> 6;
  const int wr = wid >> 1, wc = wid & 1;       // 4x2 wave grid
  const int g = lane >> 4, c = lane & 15;

  // persistent contiguous ranges: XCD (hw&7) owns tiles [xcd*454, +454);
  // slot (hw>>3) in 0..31: slots 0..5 get 15 tiles, 6..31 get 14.
  const int hw = blockIdx.x;
  const int xcd = hw & 7, slot = hw >> 3;
  int ti = xcd * 454 + slot * 14 + (slot < 6 ? slot : 6);
  const int tend = ti + 14 + (slot < 6 ? 1 : 0);

  // staging geometry (tile-invariant): 512 thr x 16B = 8KB = 32 rows of 256B
  const int srow = tid >> 4;                       // 0..31
  const int sgl = (tid & 15) ^ (srow & 15);        // swizzled source granule
  const int pxs = c;                               // read-side XOR key
  const int aoff = (wr * 32 + c) * 256;
  const int boff = (wc * 64 + c) * 256;

  const float invt = 1.0f / tp[0];
  const float xi = xip[0];

  // stage one K-half (KH in {0,1}) of a tile into buffer BUF: 8 loads/thread
#define STAGE_T(PX, PY, KH, BUF)                                          \
  do {                                                                    \
    const char* xa = (PX) + (KH) * 256;                                   \
    const char* ya = (PY) + (KH) * 256;                                   \
    char* da = (char*)(&Ab[(BUF)][0]) + wid * 1024;                       \
    char* db = (char*)(&Bb[(BUF)][0]) + wid * 1024;                       \
    gload_lds16(xa, da);                                                  \
    gload_lds16(xa + 16384, da + 8192);                                   \
    gload_lds16(xa + 32768, da + 16384);                                  \
    gload_lds16(xa + 49152, da + 24576);                                  \
    gload_lds16(ya, db);                                                  \
    gload_lds16(ya + 16384, db + 8192);                                   \
    gload_lds16(ya + 32768, db + 16384);                                  \
    gload_lds16(ya + 49152, db + 24576);                                  \
  } while (0)

  // stage labels for panels (RB,CB) into labS[PAR]: 1 load/thread (all waves
  // issue identical redundant copies -> uniform per-wave vmcnt ledger).
  // lanes 0..31 -> row labels (128 ints), 32..63 -> col labels.
#define STAGE_LAB(RB, CB, PAR)                                            \
  do {                                                                    \
    const int pb = (lane < 32 ? (RB) : (CB)) * 512;                       \
    const char* ls = (const char*)labels + (pb & 16383) + (lane & 31) * 16; \
    gload_lds16(ls, (char*)(&labS[(PAR)][0]));                            \
  } while (0)

  // compute one buffer: 4 K-slices x 8 MFMA (per-wave 32x64 subtile)
#define COMPUTE(BUF)                                                      \
  do {                                                                    \
    const char* ab = (const char*)(&Ab[(BUF)][0]) + aoff;                 \
    const char* bb = (const char*)(&Bb[(BUF)][0]) + boff;                 \
    _Pragma("unroll") for (int ks = 0; ks < 4; ++ks) {                    \
      const int px = ((ks * 4 + g) ^ pxs) * 16;                           \
      bf16x8 af[2], bg[4];                                                \
      _Pragma("unroll") for (int m = 0; m < 2; ++m)                       \
          af[m] = *(const bf16x8*)(ab + m * 4096 + px);                   \
      _Pragma("unroll") for (int n = 0; n < 4; ++n)                       \
          bg[n] = *(const bf16x8*)(bb + n * 4096 + px);                   \
      __builtin_amdgcn_s_setprio(1);                                      \
      _Pragma("unroll") for (int m = 0; m < 2; ++m)                       \
          _Pragma("unroll") for (int n = 0; n < 4; ++n)                   \
              acc[m][n] = __builtin_amdgcn_mfma_f32_16x16x32_bf16(        \
                  af[m], bg[n], acc[m][n], 0, 0, 0);                      \
      __builtin_amdgcn_s_setprio(0);                                      \
    }                                                                     \
  } while (0)

  int mode, rb, cb;
  const unsigned short *X, *Y;
  decode_tile(ti, An, Fn, Sn, Ln, mode, rb, cb, X, Y);
  const char* xs = (const char*)X + ((size_t)rb * 128 + srow) * 512 + sgl * 16;
  const char* ys = (const char*)Y + ((size_t)cb * 128 + srow) * 512 + sgl * 16;

  // prologue: [lab+k0 (9)] [k1 (8)]
  STAGE_LAB(rb, cb, 0);
  STAGE_T(xs, ys, 0, 0);
  STAGE_T(xs, ys, 1, 1);

  int par = 0;
  f32x4 acc[2][4];
  const f32x4 zero = {0.f, 0.f, 0.f, 0.f};

  while (true) {
    const bool has_next = (ti + 1 < tend);
    int nmode = 0, nrb = 0, ncb = 0;
    const unsigned short *nX = nullptr, *nY = nullptr;
    const char *nxs = nullptr, *nys = nullptr;
    if (has_next) {
      decode_tile(ti + 1, An, Fn, Sn, Ln, nmode, nrb, ncb, nX, nY);
      nxs = (const char*)nX + ((size_t)nrb * 128 + srow) * 512 + sgl * 16;
      nys = (const char*)nY + ((size_t)ncb * 128 + srow) * 512 + sgl * 16;
    }

#pragma unroll
    for (int m = 0; m < 2; ++m)
#pragma unroll
      for (int n = 0; n < 4; ++n) acc[m][n] = zero;

    // ---- step 0 (buf0, K 0..127) ----
    // ledger: [t.lab+t.k0 (9)][prev stores (s)][t.k1 (8)] -> vmcnt(8)
    // retires 9+s oldest = lab+k0+stores exactly.
    asm volatile("s_waitcnt vmcnt(8)" ::: "memory");
    barrier_raw();
    COMPUTE(0);
    barrier_raw();
    if (has_next) {
      STAGE_LAB(nrb, ncb, par ^ 1);
      STAGE_T(nxs, nys, 0, 0);     // queue += 9
    }

    // ---- step 1 (buf1, K 128..255) ----
    // ledger: [t.k1 (8)][n.lab+n.k0 (9)] -> vmcnt(9) retires t.k1.
    if (has_next) asm volatile("s_waitcnt vmcnt(9)" ::: "memory");
    else          asm volatile("s_waitcnt vmcnt(0)" ::: "memory");
    barrier_raw();
    COMPUTE(1);
    barrier_raw();

    // ---- epilogue; C/D layout: col = c, row = g*4 + reg ----
    {
      const int* lrS = &labS[par][0];
      const int* lcS = &labS[par][128];
      if (mode < 2) {
        const bool docol = (rb != cb);
        float2* Pp = (mode == 0) ? Pc : Px;
        const int NR = (mode == 0) ? 4096 : 8192;
        int collab[4];
#pragma unroll
        for (int n = 0; n < 4; ++n) collab[n] = lcS[wc * 64 + n * 16 + c];

        float cn[4] = {0.f, 0.f, 0.f, 0.f}, cd[4] = {0.f, 0.f, 0.f, 0.f};
        float rn[8], rd[8];
#pragma unroll
        for (int m = 0; m < 2; ++m) {
#pragma unroll
          for (int reg = 0; reg < 4; ++reg) {
            const int rlab = lrS[wr * 32 + m * 16 + g * 4 + reg];
            float pn = 0.f, pd = 0.f;
#pragma unroll
            for (int n = 0; n < 4; ++n) {
              float e = __expf(acc[m][n][reg] * invt);
              if (mode == 0) e = fminf(e, 1e10f);
              pd += e;
              const float en = (rlab == collab[n]) ? e : 0.f;
              pn += en;
              cd[n] += e;
              cn[n] += en;
            }
#pragma unroll
            for (int msk = 1; msk < 16; msk <<= 1) {
              pn += __shfl_xor(pn, msk);
              pd += __shfl_xor(pd, msk);
            }
            rn[m * 4 + reg] = pn;
            rd[m * 4 + reg] = pd;
          }
        }
        if (c == 0) {
#pragma unroll
          for (int m = 0; m < 2; ++m)
#pragma unroll
            for (int reg = 0; reg < 4; ++reg) {
              const int rloc = wr * 32 + m * 16 + g * 4 + reg;
              sN[wc * 128 + rloc] = rn[m * 4 + reg];
              sD[wc * 128 + rloc] = rd[m * 4 + reg];
            }
        }
#pragma unroll
        for (int n = 0; n < 4; ++n) {
          float a = cn[n], b = cd[n];
          a += __shfl_xor(a, 16); b += __shfl_xor(b, 16);
          a += __shfl_xor(a, 32); b += __shfl_xor(b, 32);
          if (g == 0) {
            cN[wr * 128 + wc * 64 + n * 16 + c] = a;
            cD[wr * 128 + wc * 64 + n * 16 + c] = b;
          }
        }
        lgkm_barrier();   // LDS-only ordering; vmcnt queue untouched
        if (tid < 128) {
          Pp[(size_t)cb * NR + rb * 128 + tid] =
              make_float2(sN[tid] + sN[128 + tid], sD[tid] + sD[128 + tid]);
        } else if (tid < 256 && docol) {
          const int t2 = tid - 128;
          Pp[(size_t)rb * NR + cb * 128 + t2] = make_float2(
              cN[t2] + cN[128 + t2] + cN[256 + t2] + cN[384 + t2],
              cD[t2] + cD[128 + t2] + cD[256 + t2] + cD[384 + t2]);
        }
      } else {
        int collab[4];
#pragma unroll
        for (int n = 0; n < 4; ++n) collab[n] = lcS[wc * 64 + n * 16 + c];
        float part = 0.f;
#pragma unroll
        for (int m = 0; m < 2; ++m)
#pragma unroll
          for (int reg = 0; reg < 4; ++reg) {
            const int rlab = lrS[wr * 32 + m * 16 + g * 4 + reg];
#pragma unroll
            for (int n = 0; n < 4; ++n) {
              const float cs = acc[m][n][reg];
              const float Dm = (1.0f - cs) * 0.5f;
              const float u = fmaxf(xi - Dm, 0.0f);
              part += (rlab == collab[n]) ? Dm * Dm : u * u;
            }
          }
#pragma unroll
        for (int msk = 1; msk < 64; msk <<= 1) part += __shfl_xor(part, msk);
        if (lane == 0) sN[wid] = part;
        lgkm_barrier();
        if (tid == 0) {
          float s = 0.f;
#pragma unroll
          for (int w = 0; w < 8; ++w) s += sN[w];
          atomicAdd(hacc, s);
        }
        lgkm_barrier();   // sN reusable next tile
      }
    }

    if (!has_next) break;
    STAGE_T(nxs, nys, 1, 1);       // lands a full tile ahead of its use
    ++ti; par ^= 1;
    mode = nmode; rb = nrb; cb = ncb; xs = nxs; ys = nys;
  }
#undef STAGE_T
#undef STAGE_LAB
#undef COMPUTE
}

// ---------------------------------------------------------------------------
// finalize: blocks 0..15 class rows, 16..47 cross rows; atomic mean into out.
__global__ __launch_bounds__(256) void finalize_kernel(
    const float2* __restrict__ Pc, const float2* __restrict__ Px,
    const float* __restrict__ hacc, float* __restrict__ out) {
  const int b = blockIdx.x, tid = threadIdx.x;
  const float2* P;
  int nslots, NR, row, oi;
  if (b < 16) { P = Pc; nslots = 32; NR = 4096; row = b * 256 + tid; oi = 0; }
  else { P = Px; nslots = 64; NR = 8192; row = (b - 16) * 256 + tid; oi = 1; }
  float n = 0.f, d = 0.f;
  for (int s = 0; s < nslots; ++s) {
    const float2 v = P[(size_t)s * NR + row];
    n += v.x;
    d += v.y;
  }
  float val = -logf(n / fmaxf(d, 1e-10f));
#pragma unroll
  for (int m = 1; m < 64; m <<= 1) val += __shfl_xor(val, m);
  __shared__ float r[4];
  if ((tid & 63) == 0) r[tid >> 6] = val;
  __syncthreads();
  if (tid == 0) atomicAdd(&out[oi], (r[0] + r[1] + r[2] + r[3]) / (float)NR);
  if (b == 0 && tid == 0) out[2] = hacc[0] * (1.0f / 16777216.0f);
}

// ---------------------------------------------------------------------------
extern "C" void kernel_launch(void* const* d_in, const int* in_sizes, int n_in,
                              void* d_out, int out_size, void* d_ws,
                              size_t ws_size, hipStream_t stream) {
  const float* LE = (const float*)d_in[0];
  const float* FZ = (const float*)d_in[1];
  const float* SE = (const float*)d_in[2];
  const float* LM = (const float*)d_in[3];
  const int* labels = (const int*)d_in[4];
  const float* tp = (const float*)d_in[5];
  const float* xip = (const float*)d_in[6];
  float* out = (float*)d_out;

  char* ws = (char*)d_ws;
  unsigned short* An = (unsigned short*)(ws);              // 2 MB
  unsigned short* Fn = (unsigned short*)(ws + 2097152);    // 4 MB
  unsigned short* Sn = (unsigned short*)(ws + 6291456);    // 2 MB
  unsigned short* Ln = (unsigned short*)(ws + 8388608);    // 2 MB
  float2* Pc = (float2*)(ws + 10485760);                   // 1 MB
  float2* Px = (float2*)(ws + 11534336);                   // 4 MB
  float* hacc = (float*)(ws + 15728640);                   // 1

  norm_kernel<<<dim3(5120), dim3(256), 0, stream>>>(LE, FZ, SE, LM, An, Fn,
                                                    Sn, Ln, hacc, out);
  // 3632 tiles = 8 XCDs x 454, 32 persistent blocks per XCD (1 block/CU).
  fused_sim<<<dim3(256), dim3(512), 0, stream>>>(An, Fn, Sn, Ln, labels, tp,
                                                 xip, Pc, Px, hacc);
  finalize_kernel<<<dim3(48), dim3(256), 0, stream>>>(Pc, Px, hacc, out);
}

// Round 10
// 167.696 us; speedup vs baseline: 1.1353x; 1.1353x over previous
//
#include <hip/hip_runtime.h>
#include <hip/hip_bf16.h>
#include <stdint.h>

// ---------------------------------------------------------------------------
// Loss_29592324669863, round 10.
//  256x256 tiles (920), 8 waves (2x4, per-wave 128x64, acc[8][4]), 16 fine
//  phases (16 MFMA + 4-8 ds_read_b128 each). LDS: dbuf A/B [256 rows][128B]
//  with granule swizzle phys = logical ^ (row&7) (r3/r5/r6-measured 0
//  conflicts; r9's 64B-row layout was ~8-way, r4 evidence). Staging: full
//  K-tile per matrix (4 gloads) issued in phases 0/1 of the previous tile;
//  uniform vmcnt(0)+barrier once per K-tile (queue holds only needed loads).
// ---------------------------------------------------------------------------

typedef __attribute__((ext_vector_type(8))) short bf16x8;   // 8 bf16 = 4 VGPR
typedef __attribute__((ext_vector_type(4))) float f32x4;

__device__ inline void gload_lds16(const void* g, void* l) {
  __builtin_amdgcn_global_load_lds(
      (__attribute__((address_space(1))) void*)g,
      (__attribute__((address_space(3))) void*)l, 16, 0, 0);
}

__device__ inline unsigned short f2bf(float x) {  // RNE f32->bf16
  unsigned int u = __builtin_bit_cast(unsigned int, x);
  u = (u + 0x7fffu + ((u >> 16) & 1u)) >> 16;
  return (unsigned short)u;
}

// ---------------------------------------------------------------------------
__global__ __launch_bounds__(256) void norm_kernel(
    const float* __restrict__ LE, const float* __restrict__ FZ,
    const float* __restrict__ SE, const float* __restrict__ LM,
    unsigned short* __restrict__ An, unsigned short* __restrict__ Fn,
    unsigned short* __restrict__ Sn, unsigned short* __restrict__ Ln,
    float* __restrict__ hacc, float* __restrict__ out) {
  const int tid = threadIdx.x;
  if (blockIdx.x == 0) {        // zero accumulators for this call
    if (tid == 0) out[0] = 0.f;
    if (tid == 1) out[1] = 0.f;
    if (tid == 2) hacc[0] = 0.f;
  }

  const int wid = tid >> 6, lane = tid & 63;
  const int row = blockIdx.x * 4 + wid;

  const float* src;
  unsigned short* dst;
  int r;
  if (row < 4096)       { src = LE; dst = An; r = row; }
  else if (row < 12288) { src = FZ; dst = Fn; r = row - 4096; }
  else if (row < 16384) { src = SE; dst = Sn; r = row - 12288; }
  else                  { src = LM; dst = Ln; r = row - 16384; }

  const float4 v = *(const float4*)(src + (size_t)r * 256 + lane * 4);
  float ss = v.x * v.x + v.y * v.y + v.z * v.z + v.w * v.w;
#pragma unroll
  for (int m = 1; m < 64; m <<= 1) ss += __shfl_xor(ss, m);
  const float scale = 1.0f / fmaxf(sqrtf(ss), 1e-8f);

  ushort4 o;
  o.x = f2bf(v.x * scale);
  o.y = f2bf(v.y * scale);
  o.z = f2bf(v.z * scale);
  o.w = f2bf(v.w * scale);
  *(ushort4*)(dst + (size_t)r * 256 + lane * 4) = o;
}

// ---------------------------------------------------------------------------
__device__ inline void tri_decode(int t, int nb, int& rb, int& cb) {
  int r = 0;
  while (t >= nb - r) { t -= nb - r; ++r; }
  rb = r;
  cb = r + t;
}

// ---------------------------------------------------------------------------
// Fused Gram kernel: one 256x256 tile per block, 8 waves (2x4), 16 phases.
// ---------------------------------------------------------------------------
__global__ __launch_bounds__(512) void fused_sim(
    const unsigned short* __restrict__ An, const unsigned short* __restrict__ Fn,
    const unsigned short* __restrict__ Sn, const unsigned short* __restrict__ Ln,
    const int* __restrict__ labels,
    const float* __restrict__ tp, const float* __restrict__ xip,
    float2* __restrict__ Pc,   // [16 slots][4096 rows] (num,den)
    float2* __restrict__ Px,   // [32 slots][8192 rows]
    float* __restrict__ hacc) {
  // LDS: [buf 2][ A 32KB | B 32KB ]; tile = [256 rows][128B], swizzled.
  __shared__ __align__(16) char AB[131072];
  __shared__ __align__(16) int labS[512];           // [row 256 | col 256]
  __shared__ float sN[1024], sD[1024];              // row partials [wc][256]
  __shared__ float cN[512], cD[512];                // col partials [wr][256]

  const int tid = threadIdx.x;
  const int lane = tid & 63, wid = tid >> 6;
  const int wr = wid >> 2, wc = wid & 3;     // 2x4 wave grid
  const int g = lane >> 4, c = lane & 15;

  // XCD swizzle: 920 = 8 * 115 (bijective)
  const int hw = blockIdx.x;
  const int bid = (hw & 7) * 115 + (hw >> 3);

  int mode, rb, cb;
  const unsigned short *X, *Y;
  if (bid < 136) {            // class: tri over 16x16 panels
    mode = 0; tri_decode(bid, 16, rb, cb); X = An; Y = An;
  } else if (bid < 664) {     // cross: tri over 32x32 panels
    mode = 1; tri_decode(bid - 136, 32, rb, cb); X = Fn; Y = Fn;
  } else {                    // hash: full 16x16
    mode = 2; const int t = bid - 664; rb = t >> 4; cb = t & 15;
    X = Sn; Y = Ln;
  }

  const float invt = 1.0f / tp[0];
  const float xi = xip[0];

  // staging geometry: thread stages rows srow + j*64 (j=0..3), 16B each,
  // source granule pre-swizzled so LDS [row][phys] holds logical phys^(row&7)
  const int srow = tid >> 3;                       // 0..63
  const int sgl = (tid & 7) ^ (srow & 7);
  const char* xsA =
      (const char*)X + ((size_t)rb * 256 + srow) * 512 + sgl * 16;
  const char* ysB =
      (const char*)Y + ((size_t)cb * 256 + srow) * 512 + sgl * 16;

  // fragment geometry: af row = wr*128 + mh*64 + m*16 + c, bg row =
  // wc*64 + n*16 + c; byte = row*128 + ((ks*4+g)^(row&7))*16, row&7 = c&7.
  const int px0 = c & 7;
  const char* aBase = AB + (wr * 128 + c) * 128;
  const char* bBase = AB + 32768 + (wc * 64 + c) * 128;

#define STG_A(KT)                                                         \
  do {                                                                    \
    const char* s_ = xsA + (KT) * 128;                                    \
    char* d_ = AB + (((KT) & 1) * 65536) + wid * 1024;                    \
    gload_lds16(s_, d_);                                                  \
    gload_lds16(s_ + 32768, d_ + 8192);                                   \
    gload_lds16(s_ + 65536, d_ + 16384);                                  \
    gload_lds16(s_ + 98304, d_ + 24576);                                  \
  } while (0)
#define STG_B(KT)                                                         \
  do {                                                                    \
    const char* s_ = ysB + (KT) * 128;                                    \
    char* d_ = AB + (((KT) & 1) * 65536) + 32768 + wid * 1024;            \
    gload_lds16(s_, d_);                                                  \
    gload_lds16(s_ + 32768, d_ + 8192);                                   \
    gload_lds16(s_ + 65536, d_ + 16384);                                  \
    gload_lds16(s_ + 98304, d_ + 24576);                                  \
  } while (0)

  // prologue: labels (2 loads, all waves redundantly) + K-tile 0 (8 loads)
  {
    const char* lr = (const char*)labels + (rb & 15) * 1024 + lane * 16;
    const char* lc = (const char*)labels + (cb & 15) * 1024 + lane * 16;
    gload_lds16(lr, (char*)labS);
    gload_lds16(lc, (char*)labS + 1024);
  }
  STG_A(0);
  STG_B(0);

  f32x4 acc[8][4];
  const f32x4 zero = {0.f, 0.f, 0.f, 0.f};
#pragma unroll
  for (int m = 0; m < 8; ++m)
#pragma unroll
    for (int n = 0; n < 4; ++n) acc[m][n] = zero;
  bf16x8 af[4], bg[4];

#pragma unroll
  for (int kt = 0; kt < 4; ++kt) {
    // queue at this point holds exactly the loads that must retire
    // (kt=0: lab+T0; kt>0: T(kt)'s 8, issued in phases 0/1 of kt-1).
    asm volatile("s_waitcnt vmcnt(0)" ::: "memory");
    __builtin_amdgcn_s_barrier();
    asm volatile("" ::: "memory");
    const int bo = (kt & 1) * 65536;
#pragma unroll
    for (int ph = 0; ph < 4; ++ph) {
      const int ks = ph >> 1, mh = ph & 1;
      const int px = ((ks * 4 + g) ^ px0) * 16;
#pragma unroll
      for (int m = 0; m < 4; ++m)
        af[m] = *(const bf16x8*)(aBase + bo + mh * 8192 + m * 2048 + px);
      if (mh == 0) {
#pragma unroll
        for (int n = 0; n < 4; ++n)
          bg[n] = *(const bf16x8*)(bBase + bo + n * 2048 + px);
      }
      if (kt < 3) {             // prefetch next K-tile into other buffer
        if (ph == 0) STG_A(kt + 1);
        else if (ph == 1) STG_B(kt + 1);
      }
      asm volatile("s_waitcnt lgkmcnt(0)" ::: "memory");
      __builtin_amdgcn_s_setprio(1);
#pragma unroll
      for (int m = 0; m < 4; ++m)
#pragma unroll
        for (int n = 0; n < 4; ++n)
          acc[mh * 4 + m][n] = __builtin_amdgcn_mfma_f32_16x16x32_bf16(
              af[m], bg[n], acc[mh * 4 + m][n], 0, 0, 0);
      __builtin_amdgcn_s_setprio(0);
    }
  }
#undef STG_A
#undef STG_B

  // ---- epilogue; C/D layout: col = c, row = g*4 + reg ----
  const int* lrS = labS;
  const int* lcS = labS + 256;
  if (mode < 2) {
    const bool docol = (rb != cb);
    float2* Pp = (mode == 0) ? Pc : Px;
    const int NR = (mode == 0) ? 4096 : 8192;
    int collab[4];
#pragma unroll
    for (int n = 0; n < 4; ++n) collab[n] = lcS[wc * 64 + n * 16 + c];

    float cn[4] = {0.f, 0.f, 0.f, 0.f}, cd[4] = {0.f, 0.f, 0.f, 0.f};
#pragma unroll
    for (int m = 0; m < 8; ++m) {
#pragma unroll
      for (int reg = 0; reg < 4; ++reg) {
        const int rloc = wr * 128 + m * 16 + g * 4 + reg;
        const int rlab = lrS[rloc];
        float pn = 0.f, pd = 0.f;
#pragma unroll
        for (int n = 0; n < 4; ++n) {
          float e = __expf(acc[m][n][reg] * invt);
          if (mode == 0) e = fminf(e, 1e10f);
          pd += e;
          const float en = (rlab == collab[n]) ? e : 0.f;
          pn += en;
          cd[n] += e;
          cn[n] += en;
        }
#pragma unroll
        for (int msk = 1; msk < 16; msk <<= 1) {
          pn += __shfl_xor(pn, msk);
          pd += __shfl_xor(pd, msk);
        }
        if (c == 0) {
          sN[wc * 256 + rloc] = pn;
          sD[wc * 256 + rloc] = pd;
        }
      }
    }
#pragma unroll
    for (int n = 0; n < 4; ++n) {
      float a = cn[n], b = cd[n];
      a += __shfl_xor(a, 16); b += __shfl_xor(b, 16);
      a += __shfl_xor(a, 32); b += __shfl_xor(b, 32);
      if (g == 0) {
        cN[wr * 256 + wc * 64 + n * 16 + c] = a;
        cD[wr * 256 + wc * 64 + n * 16 + c] = b;
      }
    }
    asm volatile("s_waitcnt lgkmcnt(0)" ::: "memory");
    __builtin_amdgcn_s_barrier();
    asm volatile("" ::: "memory");
    // conflict-free partial slots: row-contrib -> slot cb, col -> slot rb
    if (tid < 256) {
      Pp[(size_t)cb * NR + rb * 256 + tid] = make_float2(
          sN[tid] + sN[256 + tid] + sN[512 + tid] + sN[768 + tid],
          sD[tid] + sD[256 + tid] + sD[512 + tid] + sD[768 + tid]);
    } else if (docol) {
      const int t2 = tid - 256;
      Pp[(size_t)rb * NR + cb * 256 + t2] =
          make_float2(cN[t2] + cN[256 + t2], cD[t2] + cD[256 + t2]);
    }
  } else {
    int collab[4];
#pragma unroll
    for (int n = 0; n < 4; ++n) collab[n] = lcS[wc * 64 + n * 16 + c];
    float part = 0.f;
#pragma unroll
    for (int m = 0; m < 8; ++m)
#pragma unroll
      for (int reg = 0; reg < 4; ++reg) {
        const int rlab = lrS[wr * 128 + m * 16 + g * 4 + reg];
#pragma unroll
        for (int n = 0; n < 4; ++n) {
          const float cs = acc[m][n][reg];
          const float Dm = (1.0f - cs) * 0.5f;
          const float u = fmaxf(xi - Dm, 0.0f);
          part += (rlab == collab[n]) ? Dm * Dm : u * u;
        }
      }
#pragma unroll
    for (int msk = 1; msk < 64; msk <<= 1) part += __shfl_xor(part, msk);
    if (lane == 0) sN[wid] = part;
    asm volatile("s_waitcnt lgkmcnt(0)" ::: "memory");
    __builtin_amdgcn_s_barrier();
    asm volatile("" ::: "memory");
    if (tid == 0) {
      float s = 0.f;
#pragma unroll
      for (int w = 0; w < 8; ++w) s += sN[w];
      atomicAdd(hacc, s);
    }
  }
}

// ---------------------------------------------------------------------------
// finalize: blocks 0..15 class rows, 16..47 cross rows; atomic mean into out.
__global__ __launch_bounds__(256) void finalize_kernel(
    const float2* __restrict__ Pc, const float2* __restrict__ Px,
    const float* __restrict__ hacc, float* __restrict__ out) {
  const int b = blockIdx.x, tid = threadIdx.x;
  const float2* P;
  int nslots, NR, row, oi;
  if (b < 16) { P = Pc; nslots = 16; NR = 4096; row = b * 256 + tid; oi = 0; }
  else { P = Px; nslots = 32; NR = 8192; row = (b - 16) * 256 + tid; oi = 1; }
  float n = 0.f, d = 0.f;
  for (int s = 0; s < nslots; ++s) {
    const float2 v = P[(size_t)s * NR + row];
    n += v.x;
    d += v.y;
  }
  float val = -logf(n / fmaxf(d, 1e-10f));
#pragma unroll
  for (int m = 1; m < 64; m <<= 1) val += __shfl_xor(val, m);
  __shared__ float r[4];
  if ((tid & 63) == 0) r[tid >> 6] = val;
  __syncthreads();
  if (tid == 0) atomicAdd(&out[oi], (r[0] + r[1] + r[2] + r[3]) / (float)NR);
  if (b == 0 && tid == 0) out[2] = hacc[0] * (1.0f / 16777216.0f);
}

// ---------------------------------------------------------------------------
extern "C" void kernel_launch(void* const* d_in, const int* in_sizes, int n_in,
                              void* d_out, int out_size, void* d_ws,
                              size_t ws_size, hipStream_t stream) {
  const float* LE = (const float*)d_in[0];
  const float* FZ = (const float*)d_in[1];
  const float* SE = (const float*)d_in[2];
  const float* LM = (const float*)d_in[3];
  const int* labels = (const int*)d_in[4];
  const float* tp = (const float*)d_in[5];
  const float* xip = (const float*)d_in[6];
  float* out = (float*)d_out;

  char* ws = (char*)d_ws;
  unsigned short* An = (unsigned short*)(ws);              // 2 MB
  unsigned short* Fn = (unsigned short*)(ws + 2097152);    // 4 MB
  unsigned short* Sn = (unsigned short*)(ws + 6291456);    // 2 MB
  unsigned short* Ln = (unsigned short*)(ws + 8388608);    // 2 MB
  float2* Pc = (float2*)(ws + 10485760);                   // 512 KB
  float2* Px = (float2*)(ws + 11534336);                   // 2 MB
  float* hacc = (float*)(ws + 15728640);                   // 1

  norm_kernel<<<dim3(5120), dim3(256), 0, stream>>>(LE, FZ, SE, LM, An, Fn,
                                                    Sn, Ln, hacc, out);
  // 920 tiles: 136 class (tri16) + 528 cross (tri32) + 256 hash
  fused_sim<<<dim3(920), dim3(512), 0, stream>>>(An, Fn, Sn, Ln, labels, tp,
                                                 xip, Pc, Px, hacc);
  finalize_kernel<<<dim3(48), dim3(256), 0, stream>>>(Pc, Px, hacc, out);
}